// Round 10
// baseline (323.716 us; speedup 1.0000x reference)
//
#include <hip/hip_runtime.h>

#define NU 1024
#define NL 2048
#define NB 65536
#define RPB 16

typedef float f32x4 __attribute__((ext_vector_type(4)));

// Module-scope scratch (16 KB) instead of d_ws: removes any dependence on
// ws_size (unchecked OOB into d_ws was the one kernel-side crash candidate
// for the "container failed twice" rounds). Allocated at module load; every
// element is rewritten on every launch before being read:
//   g_ws[0    .. 1023] : prev_j       (f32, reference cumsum rounding)
//   g_ws[1024]         : sum(Pd)
//   g_ws[1040 .. 2063] : pmax_sorted  (Pmax scattered into sorted order)
//   g_ws[2080 .. 3103] : rank_j       (int, sorted position of unit j)
__device__ __align__(16) float g_ws[3104];

// ---- Kernel A: ranks (16 blocks) + Pd sum (1 block) --------------------
// Stable-argsort rank via 64-bit key: Cost > 0 so positive-float bits are
// monotone as unsigned; key = (bits(Cost[i])<<32) | i implements
// (ci < cj) || (ci == cj && i < j) as a single u64 compare.
__global__ __launch_bounds__(64) void rank_kernel(const float* __restrict__ Cost,
                                                  const float* __restrict__ Pmax,
                                                  const float* __restrict__ Pd) {
    const int bid = blockIdx.x;
    const int tid = threadIdx.x;
    if (bid < 16) {
        const int j = bid * 64 + tid;
        const unsigned long long keyj =
            ((unsigned long long)__float_as_uint(Cost[j]) << 32) | (unsigned)j;
        int r = 0;
        #pragma unroll 8
        for (int i = 0; i < NU; ++i) {   // Cost[i] uniform -> scalar loads
            const unsigned long long ki =
                ((unsigned long long)__float_as_uint(Cost[i]) << 32) | (unsigned)i;
            r += (ki < keyj) ? 1 : 0;
        }
        ((int*)(g_ws + 2080))[j] = r;
        (g_ws + 1040)[r] = Pmax[j];      // scatter into sorted order
    } else {
        // sum(Pd) in double (closest match to the reference's f32 tree sum)
        double acc = 0.0;
        for (int i = tid; i < NL; i += 64) acc += (double)Pd[i];
        #pragma unroll
        for (int off = 32; off; off >>= 1) acc += __shfl_down(acc, off, 64);
        if (tid == 0) g_ws[NU] = (float)acc;
    }
}

// ---- Kernel B: sequential f32 cumsum (reference rounding) + prev gather ----
__global__ __launch_bounds__(256) void scan_kernel() {
    __shared__ float pm_s[NU];
    __shared__ float cum_s[NU];
    const int tid = threadIdx.x;
    for (int j = tid; j < NU; j += 256) pm_s[j] = (g_ws + 1040)[j];
    __syncthreads();
    if (tid == 0) {
        float run = 0.0f;
        #pragma unroll 8
        for (int k = 0; k < NU; ++k) { run = __fadd_rn(run, pm_s[k]); cum_s[k] = run; }
    }
    __syncthreads();
    const int* __restrict__ rank = (const int*)(g_ws + 2080);
    for (int j = tid; j < NU; j += 256) {
        const int r = rank[j];
        g_ws[j] = __fsub_rn(cum_s[r], pm_s[r]);  // prev = cum - Pmax_s, f32 like ref
    }
}

// ---- Kernel C: the 256 MiB write-bound broadcast ------------------------
__global__ __launch_bounds__(256) void dispatch_kernel(const float* __restrict__ x,
                                                       const float* __restrict__ Pmax,
                                                       const float* __restrict__ wcap,
                                                       float* __restrict__ out) {
    const int tid = threadIdx.x;
    const int j4 = tid * 4;

    const f32x4 prev4 = *reinterpret_cast<const f32x4*>(g_ws + j4);
    const f32x4 pmax4 = *reinterpret_cast<const f32x4*>(Pmax + j4);
    const float sumPd = g_ws[NU];
    const float cap = wcap[0];

    const int b0 = blockIdx.x * RPB;
    #pragma unroll 4
    for (int r = 0; r < RPB; ++r) {
        const int b = b0 + r;
        // match reference rounding exactly: mul, then sub (block FMA contraction)
        const float d = __fsub_rn(sumPd, __fmul_rn(cap, x[b]));
        f32x4 o;
        o.x = fminf(fmaxf(__fsub_rn(d, prev4.x), 0.0f), pmax4.x);
        o.y = fminf(fmaxf(__fsub_rn(d, prev4.y), 0.0f), pmax4.y);
        o.z = fminf(fmaxf(__fsub_rn(d, prev4.z), 0.0f), pmax4.z);
        o.w = fminf(fmaxf(__fsub_rn(d, prev4.w), 0.0f), pmax4.w);
        __builtin_nontemporal_store(o,
            reinterpret_cast<f32x4*>(out + (size_t)b * NU + j4));
    }
}

extern "C" void kernel_launch(void* const* d_in, const int* in_sizes, int n_in,
                              void* d_out, int out_size, void* d_ws, size_t ws_size,
                              hipStream_t stream) {
    const float* x    = (const float*)d_in[0];
    const float* Cost = (const float*)d_in[1];
    const float* Pmax = (const float*)d_in[2];
    const float* Pd   = (const float*)d_in[3];
    const float* wcap = (const float*)d_in[4];
    float* out = (float*)d_out;
    (void)d_ws; (void)ws_size;   // unused: module-scope g_ws is the scratch

    rank_kernel<<<17, 64, 0, stream>>>(Cost, Pmax, Pd);
    scan_kernel<<<1, 256, 0, stream>>>();
    dispatch_kernel<<<NB / RPB, 256, 0, stream>>>(x, Pmax, wcap, out);
}

// Round 14
// 311.512 us; speedup vs baseline: 1.0392x; 1.0392x over previous
//
#include <hip/hip_runtime.h>

#define NU 1024
#define NL 2048
#define NB 65536
#define RPB 16

typedef float f32x4 __attribute__((ext_vector_type(4)));

// Module-scope scratch (16 KB). Every element rewritten each launch:
//   g_ws[0    .. 1023] : prev_j       (f32)
//   g_ws[1024]         : sum(Pd)
//   g_ws[1040 .. 2063] : pmax_sorted
//   g_ws[2080 .. 3103] : rank_j (int)
__device__ __align__(16) float g_ws[3104];

// ---- Kernel A: ranks (16 blocks) + Pd sum (1 block) --------------------
__global__ __launch_bounds__(64) void rank_kernel(const float* __restrict__ Cost,
                                                  const float* __restrict__ Pmax,
                                                  const float* __restrict__ Pd) {
    const int bid = blockIdx.x;
    const int tid = threadIdx.x;
    if (bid < 16) {
        const int j = bid * 64 + tid;
        const unsigned long long keyj =
            ((unsigned long long)__float_as_uint(Cost[j]) << 32) | (unsigned)j;
        int r = 0;
        #pragma unroll 8
        for (int i = 0; i < NU; ++i) {
            const unsigned long long ki =
                ((unsigned long long)__float_as_uint(Cost[i]) << 32) | (unsigned)i;
            r += (ki < keyj) ? 1 : 0;
        }
        ((int*)(g_ws + 2080))[j] = r;
        (g_ws + 1040)[r] = Pmax[j];
    } else {
        double acc = 0.0;
        for (int i = tid; i < NL; i += 64) acc += (double)Pd[i];
        #pragma unroll
        for (int off = 32; off; off >>= 1) acc += __shfl_down(acc, off, 64);
        if (tid == 0) g_ws[NU] = (float)acc;
    }
}

// ---- Kernel B: sequential f32 cumsum + prev gather ---------------------
__global__ __launch_bounds__(256) void scan_kernel() {
    __shared__ float pm_s[NU];
    __shared__ float cum_s[NU];
    const int tid = threadIdx.x;
    for (int j = tid; j < NU; j += 256) pm_s[j] = (g_ws + 1040)[j];
    __syncthreads();
    if (tid == 0) {
        float run = 0.0f;
        #pragma unroll 8
        for (int k = 0; k < NU; ++k) { run = __fadd_rn(run, pm_s[k]); cum_s[k] = run; }
    }
    __syncthreads();
    const int* __restrict__ rank = (const int*)(g_ws + 2080);
    for (int j = tid; j < NU; j += 256) {
        const int r = rank[j];
        g_ws[j] = __fsub_rn(cum_s[r], pm_s[r]);
    }
}

// ---- Kernel C: 256 MiB write-bound broadcast (PLAIN stores this round) --
__global__ __launch_bounds__(256) void dispatch_kernel(const float* __restrict__ x,
                                                       const float* __restrict__ Pmax,
                                                       const float* __restrict__ wcap,
                                                       float* __restrict__ out) {
    const int tid = threadIdx.x;
    const int j4 = tid * 4;

    const f32x4 prev4 = *reinterpret_cast<const f32x4*>(g_ws + j4);
    const f32x4 pmax4 = *reinterpret_cast<const f32x4*>(Pmax + j4);
    const float sumPd = g_ws[NU];
    const float cap = wcap[0];

    const int b0 = blockIdx.x * RPB;
    #pragma unroll 4
    for (int r = 0; r < RPB; ++r) {
        const int b = b0 + r;
        const float d = __fsub_rn(sumPd, __fmul_rn(cap, x[b]));
        f32x4 o;
        o.x = fminf(fmaxf(__fsub_rn(d, prev4.x), 0.0f), pmax4.x);
        o.y = fminf(fmaxf(__fsub_rn(d, prev4.y), 0.0f), pmax4.y);
        o.z = fminf(fmaxf(__fsub_rn(d, prev4.z), 0.0f), pmax4.z);
        o.w = fminf(fmaxf(__fsub_rn(d, prev4.w), 0.0f), pmax4.w);
        *reinterpret_cast<f32x4*>(out + (size_t)b * NU + j4) = o;   // plain store (A/B vs nt)
    }
}

extern "C" void kernel_launch(void* const* d_in, const int* in_sizes, int n_in,
                              void* d_out, int out_size, void* d_ws, size_t ws_size,
                              hipStream_t stream) {
    const float* x    = (const float*)d_in[0];
    const float* Cost = (const float*)d_in[1];
    const float* Pmax = (const float*)d_in[2];
    const float* Pd   = (const float*)d_in[3];
    const float* wcap = (const float*)d_in[4];
    float* out = (float*)d_out;
    (void)d_ws; (void)ws_size;

    rank_kernel<<<17, 64, 0, stream>>>(Cost, Pmax, Pd);
    scan_kernel<<<1, 256, 0, stream>>>();
    dispatch_kernel<<<NB / RPB, 256, 0, stream>>>(x, Pmax, wcap, out);
}